// Round 11
// baseline (364.616 us; speedup 1.0000x reference)
//
#include <hip/hip_runtime.h>
#include <hip/hip_fp16.h>

// ---------------------------------------------------------------------------
// GCN 3-layer forward. fp32 accumulate; fp16 message buffer G.
// R4: fp16 G. R11: MFMA fp16 GEMMs, fp16 hbuf, W pre-transposed once.
// R12: bucketed CSR build. R14: cross-node 3-deep agg pipeline (64.5us).
// R15 FAILED: wider MLP -> VGPR split. Cap: ~85 outstanding gathers/CU.
// R16 FAILED: stride bug. R17: split kernels, 342.6us.
// R18: barrier-free agg+gemm fusion, 32 nodes/wave -> 84us/fused, 337us
//   total (best so far) but agg starved (12.2 waves/CU work < 14 cap).
// R19/R20 FAILED: 16 nodes/wave raises waves to 24.4/CU but DOUBLES the
//   per-wave B-panel loads -> 90-92us. Amortization vs occupancy conflict.
// R21 (this round): 16 nodes/wave + PAIRWISE-SHARED GEMM. 2-wave blocks;
//   each wave aggs its own 16 rows (full occupancy), one 2-wave
//   __syncthreads, then both waves gemm the 32-row tile split by output
//   cols (wave0 cols 0-63, wave1 64-127): each B-fragment serves 32 rows
//   -> B-loads/node = 0.5x R18, 0.25x R20. Barrier couples only 2 waves.
// ---------------------------------------------------------------------------

#define CAP 8192     // per-bucket capacity (mean 4096, +64 sigma)
#define NBMAX 512

typedef _Float16 f16;
typedef __attribute__((ext_vector_type(8))) _Float16 f16x8;
typedef __attribute__((ext_vector_type(4))) _Float16 f16x4;
typedef __attribute__((ext_vector_type(4))) float f32x4;

// ---------------------------------------------------------------------------
// K1: bucket partition (blocks < gP1) + W fp16-transpose prep (rest).
// Packed entry: (src << 8) | (dst & 255); bucket = dst >> 8.
// ---------------------------------------------------------------------------
__global__ __launch_bounds__(256)
void bucket_prep_kernel(const int* __restrict__ src, const int* __restrict__ dst,
                        int E, int gP1, int NB,
                        int* __restrict__ bucket_cnt, unsigned* __restrict__ bucketbuf,
                        const float* __restrict__ W0, const float* __restrict__ W1,
                        const float* __restrict__ W2,
                        __half* __restrict__ w0t, __half* __restrict__ w1t,
                        __half* __restrict__ w2t) {
  int b = blockIdx.x;
  if (b < gP1) {
    __shared__ int hist[NBMAX];
    __shared__ int cbase[NBMAX];
    int tid = threadIdx.x;
    for (int i = tid; i < NB; i += 256) hist[i] = 0;
    __syncthreads();
    int e0 = b * 4096;
    int eend = min(e0 + 4096, E);
    for (int e = e0 + tid; e < eend; e += 256)
      atomicAdd(&hist[((unsigned)dst[e]) >> 8], 1);
    __syncthreads();
    for (int i = tid; i < NB; i += 256) {
      int h = hist[i];
      cbase[i] = h ? atomicAdd(&bucket_cnt[i], h) : 0;
    }
    __syncthreads();
    for (int i = tid; i < NB; i += 256) hist[i] = 0;
    __syncthreads();
    for (int e = e0 + tid; e < eend; e += 256) {
      int d = dst[e];
      int s = src[e];
      int bk = ((unsigned)d) >> 8;
      int idx = cbase[bk] + atomicAdd(&hist[bk], 1);
      if (idx < CAP)
        bucketbuf[(size_t)bk * CAP + idx] = (((unsigned)s) << 8) | (unsigned)(d & 255);
    }
  } else {
    int i = (b - gP1) * 256 + threadIdx.x;
    if (i < 16384) {
      int n = i >> 7, k = i & 127;
      w0t[i] = __float2half_rn(W0[k * 128 + n]);           // w0t[n][k] = W0[k][n]
    } else if (i < 32768) {
      int j = i - 16384;
      int n = j >> 7, k = j & 127;
      w1t[j] = __float2half_rn(W1[k * 128 + n]);
    } else if (i < 38912) {
      int j = i - 32768;
      int n = j >> 7, k = j & 127;                          // n in [0,48)
      w2t[j] = (n < 40) ? __float2half_rn(W2[k * 40 + n]) : __float2half_rn(0.f);
    }
  }
}

// ---------------------------------------------------------------------------
// Phase 2 (per bucket, fused into K2): counts, scan, rowptr, dinv, col.
// ---------------------------------------------------------------------------
struct P2Shared {
  unsigned plist[CAP];   // 32 KB
  int cnts[256];
  int sm[256];
};

__device__ __forceinline__
void phase2_body(const unsigned* __restrict__ bucketbuf, const int* __restrict__ bucket_cnt,
                 int* __restrict__ rowptr, float* __restrict__ dinv,
                 int* __restrict__ col, int N, int E, int NB, int b, P2Shared& sh) {
  int tid = threadIdx.x;
  int cnt_b = min(bucket_cnt[b], CAP);

  int part = 0;
  for (int i = tid; i < b; i += 256) part += bucket_cnt[i];
  sh.sm[tid] = part;
  __syncthreads();
#pragma unroll
  for (int off = 128; off > 0; off >>= 1) {
    if (tid < off) sh.sm[tid] += sh.sm[tid + off];
    __syncthreads();
  }
  int base = sh.sm[0];
  __syncthreads();

  for (int i = tid; i < cnt_b; i += 256)
    sh.plist[i] = bucketbuf[(size_t)b * CAP + i];
  sh.cnts[tid] = 0;
  __syncthreads();
  for (int i = tid; i < cnt_b; i += 256)
    atomicAdd(&sh.cnts[sh.plist[i] & 255u], 1);
  __syncthreads();

  int myc = sh.cnts[tid];
  sh.sm[tid] = myc;
  __syncthreads();
#pragma unroll
  for (int off = 1; off < 256; off <<= 1) {
    int u = (tid >= off) ? sh.sm[tid - off] : 0;
    __syncthreads();
    sh.sm[tid] += u;
    __syncthreads();
  }
  int exc = sh.sm[tid] - myc;

  int n = (b << 8) + tid;
  if (n < N) {
    rowptr[n] = base + exc;
    dinv[n] = 1.0f / sqrtf((float)myc + 1.0f);
  }
  if (b == NB - 1 && tid == 0) rowptr[N] = E;
  __syncthreads();

  sh.cnts[tid] = base + exc;
  __syncthreads();
  for (int i = tid; i < cnt_b; i += 256) {
    unsigned p = sh.plist[i];
    int pos = atomicAdd(&sh.cnts[p & 255u], 1);
    col[pos] = (int)(p >> 8);
  }
}

// ---------------------------------------------------------------------------
// MFMA fp16 GEMM body (used by K2 for layer-0): G = X @ W, unscaled.
// ---------------------------------------------------------------------------
template <typename TIN, bool SCALE>
__device__ __forceinline__
void mfma_gemm128_body(const TIN* __restrict__ X, const __half* __restrict__ Wt,
                       const float* __restrict__ dinv, __half* __restrict__ G,
                       int nrows, int blk, f16 (*xs)[72], f16 (*ws)[72]) {
  const int tid = threadIdx.x;
  const int wave = tid >> 6;
  const int lane = tid & 63;
  const int mrow = lane & 15;
  const int kg = lane >> 4;
  const int row0 = blk * 128;

  f32x4 acc[2][8];
#pragma unroll
  for (int i = 0; i < 2; ++i)
#pragma unroll
    for (int j = 0; j < 8; ++j) acc[i][j] = (f32x4){0.f, 0.f, 0.f, 0.f};

  for (int k0 = 0; k0 < 128; k0 += 64) {
    if constexpr (sizeof(TIN) == 4) {
#pragma unroll
      for (int t = tid; t < 2048; t += 256) {
        int r = t >> 4;
        int kk = (t & 15) * 4;
        float4 v = make_float4(0.f, 0.f, 0.f, 0.f);
        if (row0 + r < nrows)
          v = *(const float4*)((const float*)X + (size_t)(row0 + r) * 128 + k0 + kk);
        f16x4 hv = {(f16)v.x, (f16)v.y, (f16)v.z, (f16)v.w};
        *(f16x4*)&xs[r][kk] = hv;
      }
    } else {
#pragma unroll
      for (int t = tid; t < 1024; t += 256) {
        int r = t >> 3;
        int kk = (t & 7) * 8;
        f16x8 v = (f16x8){0, 0, 0, 0, 0, 0, 0, 0};
        if (row0 + r < nrows)
          v = *(const f16x8*)((const f16*)X + (size_t)(row0 + r) * 128 + k0 + kk);
        *(f16x8*)&xs[r][kk] = v;
      }
    }
#pragma unroll
    for (int t = tid; t < 1024; t += 256) {
      int r = t >> 3;
      int kk = (t & 7) * 8;
      *(f16x8*)&ws[r][kk] =
          *(const f16x8*)((const f16*)Wt + (size_t)r * 128 + k0 + kk);
    }
    __syncthreads();
#pragma unroll
    for (int ks = 0; ks < 64; ks += 32) {
      f16x8 a0 = *(const f16x8*)&xs[wave * 32 + mrow][ks + kg * 8];
      f16x8 a1 = *(const f16x8*)&xs[wave * 32 + 16 + mrow][ks + kg * 8];
#pragma unroll
      for (int nt = 0; nt < 8; ++nt) {
        f16x8 b = *(const f16x8*)&ws[nt * 16 + mrow][ks + kg * 8];
        acc[0][nt] = __builtin_amdgcn_mfma_f32_16x16x32_f16(a0, b, acc[0][nt], 0, 0, 0);
        acc[1][nt] = __builtin_amdgcn_mfma_f32_16x16x32_f16(a1, b, acc[1][nt], 0, 0, 0);
      }
    }
    __syncthreads();
  }
#pragma unroll
  for (int mt = 0; mt < 2; ++mt) {
    int rbase = row0 + wave * 32 + mt * 16 + kg * 4;
#pragma unroll
    for (int i = 0; i < 4; ++i) {
      int grow = rbase + i;
      if (grow < nrows) {
        float s = SCALE ? dinv[grow] : 1.0f;
        __half* gp = G + (size_t)grow * 128 + mrow;
#pragma unroll
        for (int nt = 0; nt < 8; ++nt)
          gp[nt * 16] = __float2half_rn(s * acc[mt][nt][i]);
      }
    }
  }
}

// Fat K2: blocks [0,NB) build CSR (latency-bound, start first); rest gemm0.
__global__ __launch_bounds__(256)
void gemm128_build_kernel(const float* __restrict__ X, const __half* __restrict__ Wt,
                          __half* __restrict__ G, int nrows,
                          const unsigned* __restrict__ bucketbuf,
                          const int* __restrict__ bucket_cnt,
                          int* __restrict__ rowptr, float* __restrict__ dinv,
                          int* __restrict__ col, int N, int E, int NB) {
  __shared__ char shraw[2 * 128 * 72 * sizeof(f16)];  // 36864 >= sizeof(P2Shared)
  if ((int)blockIdx.x < NB) {
    phase2_body(bucketbuf, bucket_cnt, rowptr, dinv, col, N, E, NB,
                blockIdx.x, *(P2Shared*)shraw);
  } else {
    f16 (*xs)[72] = (f16(*)[72])shraw;
    f16 (*ws)[72] = (f16(*)[72])(shraw + 128 * 72 * sizeof(f16));
    mfma_gemm128_body<float, false>(X, Wt, nullptr, G, nrows, blockIdx.x - NB, xs, ws);
  }
}

// ---------------------------------------------------------------------------
// FUSED aggregate + GEMM with pairwise-shared gemm (R21).
// 128-thr blocks (2 waves), 16 nodes/wave = 32 nodes/block.
//   Phase 1 (per wave, independent): aggregate own 16 nodes (R14 3-deep
//     pipeline, 20-edge rounds, weight-0 fma masking) with bias+ReLU ->
//     fp16 rows in xs[wave*16 + j].
//   __syncthreads() (couples only 2 waves; E[max of 2] ~ +3%).
//   Phase 2 (cooperative): both waves gemm the 32-row tile; wave w covers
//     output tiles nt = w*NTH .. — each B-fragment serves 32 rows (2 MFMAs)
//     -> B traffic halved vs R18, quartered vs R20.
// Grid = N/32 = 3125 blocks (24.4 waves/CU of work, above the gather cap).
// ---------------------------------------------------------------------------
template <bool WEIGHTED, int NT, int OSTR>
__global__ __launch_bounds__(128, 6)
void agg_gemm_kernel(const __half* __restrict__ G_in, const int* __restrict__ rowptr,
                     const int* __restrict__ col, const float* __restrict__ dinv,
                     const float* __restrict__ bias, const __half* __restrict__ Wt,
                     __half* __restrict__ G_out, int n) {
  __shared__ f16 xs[32][136];   // 8704 B
  const int tid = threadIdx.x;
  const int wave = tid >> 6;    // 0..1
  const int lane = tid & 63;
  const int sub = lane >> 4;
  const int c = lane & 15;
  const float4* g4 = (const float4*)G_in;   // row stride = 16 float4

  const int nb0 = blockIdx.x * 32;
  const int n0 = nb0 + wave * 16;

  if (n0 < n) {
    // ---- agg phase: nodes n0 .. n0+15 ----
    int eA = rowptr[n0], endA = rowptr[n0 + 1];
    int nn1 = min(n0 + 1, n - 1);
    int eB = rowptr[nn1], endB = rowptr[nn1 + 1];

    int lastA = (endA > eA) ? endA - 1 : 0;
    int iA = eA + sub;
    int cA0 = col[min(iA,      lastA)];
    int cA1 = col[min(iA + 4,  lastA)];
    int cA2 = col[min(iA + 8,  lastA)];
    int cA3 = col[min(iA + 12, lastA)];
    int cA4 = col[min(iA + 16, lastA)];

    for (int j = 0; j < 16; ++j) {
      int node = n0 + j;
      if (node >= n) break;

      float4 r0 = g4[(size_t)cA0 * 16 + c];
      float4 r1 = g4[(size_t)cA1 * 16 + c];
      float4 r2 = g4[(size_t)cA2 * 16 + c];
      float4 r3 = g4[(size_t)cA3 * 16 + c];
      float4 r4 = g4[(size_t)cA4 * 16 + c];
      float4 rs = g4[(size_t)node * 16 + c];
      float dv0 = 1.f, dv1 = 1.f, dv2 = 1.f, dv3 = 1.f, dv4 = 1.f;
      if (WEIGHTED) {
        dv0 = dinv[cA0]; dv1 = dinv[cA1]; dv2 = dinv[cA2];
        dv3 = dinv[cA3]; dv4 = dinv[cA4];
      }
      float di = dinv[node];

      int n2 = min(node + 2, n - 1);
      int eC = rowptr[n2];
      int endC = rowptr[n2 + 1];

      int lastB = (endB > eB) ? endB - 1 : 0;
      int iB = eB + sub;
      int cB0 = col[min(iB,      lastB)];
      int cB1 = col[min(iB + 4,  lastB)];
      int cB2 = col[min(iB + 8,  lastB)];
      int cB3 = col[min(iB + 12, lastB)];
      int cB4 = col[min(iB + 16, lastB)];

      float a0 = 0.f, a1 = 0.f, a2 = 0.f, a3 = 0.f,
            a4 = 0.f, a5 = 0.f, a6 = 0.f, a7 = 0.f;
      auto accumw = [&](float4 raw, float w) {
        const __half2* h = (const __half2*)&raw;
        float2 f0 = __half22float2(h[0]);
        float2 f1 = __half22float2(h[1]);
        float2 f2 = __half22float2(h[2]);
        float2 f3 = __half22float2(h[3]);
        a0 = fmaf(w, f0.x, a0); a1 = fmaf(w, f0.y, a1);
        a2 = fmaf(w, f1.x, a2); a3 = fmaf(w, f1.y, a3);
        a4 = fmaf(w, f2.x, a4); a5 = fmaf(w, f2.y, a5);
        a6 = fmaf(w, f3.x, a6); a7 = fmaf(w, f3.y, a7);
      };
      accumw(rs, (sub == 0) ? (WEIGHTED ? di : 1.f) : 0.f);  // self-loop
      accumw(r0, (iA      < endA) ? dv0 : 0.f);
      accumw(r1, (iA + 4  < endA) ? dv1 : 0.f);
      accumw(r2, (iA + 8  < endA) ? dv2 : 0.f);
      accumw(r3, (iA + 12 < endA) ? dv3 : 0.f);
      accumw(r4, (iA + 16 < endA) ? dv4 : 0.f);

      for (int t = eA + 20; t < endA; t += 4) {
        int it = t + sub;
        if (it < endA) {
          int sc = col[it];
          accumw(g4[(size_t)sc * 16 + c], WEIGHTED ? dinv[sc] : 1.f);
        }
      }

      a0 += __shfl_xor(a0, 16); a1 += __shfl_xor(a1, 16);
      a2 += __shfl_xor(a2, 16); a3 += __shfl_xor(a3, 16);
      a4 += __shfl_xor(a4, 16); a5 += __shfl_xor(a5, 16);
      a6 += __shfl_xor(a6, 16); a7 += __shfl_xor(a7, 16);
      a0 += __shfl_xor(a0, 32); a1 += __shfl_xor(a1, 32);
      a2 += __shfl_xor(a2, 32); a3 += __shfl_xor(a3, 32);
      a4 += __shfl_xor(a4, 32); a5 += __shfl_xor(a5, 32);
      a6 += __shfl_xor(a6, 32); a7 += __shfl_xor(a7, 32);

      if (sub == 0) {
        const float4* b4 = (const float4*)bias;
        float4 bb0 = b4[c * 2];
        float4 bb1 = b4[c * 2 + 1];
        float o0 = fmaxf(di * a0 + bb0.x, 0.f);
        float o1 = fmaxf(di * a1 + bb0.y, 0.f);
        float o2 = fmaxf(di * a2 + bb0.z, 0.f);
        float o3 = fmaxf(di * a3 + bb0.w, 0.f);
        float o4 = fmaxf(di * a4 + bb1.x, 0.f);
        float o5 = fmaxf(di * a5 + bb1.y, 0.f);
        float o6 = fmaxf(di * a6 + bb1.z, 0.f);
        float o7 = fmaxf(di * a7 + bb1.w, 0.f);
        f16x8 hv = {(f16)o0, (f16)o1, (f16)o2, (f16)o3,
                    (f16)o4, (f16)o5, (f16)o6, (f16)o7};
        *(f16x8*)&xs[wave * 16 + j][c * 8] = hv;
      }

      eA = eB; endA = endB; eB = eC; endB = endC;
      iA = eA + sub;
      cA0 = cB0; cA1 = cB1; cA2 = cB2; cA3 = cB3; cA4 = cB4;
    }
  }

  __syncthreads();   // all 128 threads reach this (no early return above)

  // ---- cooperative gemm: 32 rows x NT tiles; wave w covers its nt half ----
  const int mrow = c;   // lane & 15
  const int kg = sub;   // lane >> 4
  constexpr int NTH = (NT + 1) / 2;
  f32x4 acc[2][NTH];
#pragma unroll
  for (int mt = 0; mt < 2; ++mt)
#pragma unroll
    for (int t = 0; t < NTH; ++t) acc[mt][t] = (f32x4){0.f, 0.f, 0.f, 0.f};

#pragma unroll
  for (int ks = 0; ks < 128; ks += 32) {
    f16x8 fa0 = *(const f16x8*)&xs[mrow][ks + kg * 8];        // rows 0-15
    f16x8 fa1 = *(const f16x8*)&xs[16 + mrow][ks + kg * 8];   // rows 16-31
#pragma unroll
    for (int t = 0; t < NTH; ++t) {
      int nt = wave * NTH + t;
      if (nt < NT) {   // wave-uniform; folds away for NT=8
        f16x8 b = *(const f16x8*)((const f16*)Wt +
                                  (size_t)(nt * 16 + mrow) * 128 + ks + kg * 8);
        acc[0][t] = __builtin_amdgcn_mfma_f32_16x16x32_f16(fa0, b, acc[0][t], 0, 0, 0);
        acc[1][t] = __builtin_amdgcn_mfma_f32_16x16x32_f16(fa1, b, acc[1][t], 0, 0, 0);
      }
    }
  }

#pragma unroll
  for (int mt = 0; mt < 2; ++mt) {
    int rbase = nb0 + mt * 16 + kg * 4;
#pragma unroll
    for (int i = 0; i < 4; ++i) {
      int grow = rbase + i;
      if (grow < n) {
        float s = dinv[grow];
#pragma unroll
        for (int t = 0; t < NTH; ++t) {
          int nt = wave * NTH + t;
          if (nt < NT && (OSTR == 128 || nt * 16 + mrow < 40))
            G_out[(size_t)grow * OSTR + nt * 16 + mrow] =
                __float2half_rn(s * acc[mt][t][i]);
        }
      }
    }
  }
}

// M=40 aggregate (unweighted: G pre-scaled), R14 form. G40 rows at 128B
// stride = 16 float2 per row -> one aligned line per gather.
__global__ __launch_bounds__(256)
void aggregate40_kernel(const __half* __restrict__ G, const int* __restrict__ rowptr,
                        const int* __restrict__ col, const float* __restrict__ dinv,
                        const float* __restrict__ bias, float* __restrict__ out,
                        int n) {
  constexpr int NPW = 4;
  int wid = threadIdx.x >> 6;
  int lane = threadIdx.x & 63;
  int n0 = (blockIdx.x * 4 + wid) * NPW;
  if (n0 >= n) return;

  int sub = lane / 10;    // 0..6 (6 = idle)
  int c = lane % 10;
  bool act = sub < 6;
  const float2* g2 = (const float2*)G;   // row stride = 16 float2 (128B)

  int eA = rowptr[n0], endA = rowptr[n0 + 1];
  int n1 = min(n0 + 1, n - 1);
  int eB = rowptr[n1], endB = rowptr[n1 + 1];

  int lastA = (endA > eA) ? endA - 1 : 0;
  int iA = eA + sub * 4;
  int cA0 = col[min(iA,     lastA)];
  int cA1 = col[min(iA + 1, lastA)];
  int cA2 = col[min(iA + 2, lastA)];
  int cA3 = col[min(iA + 3, lastA)];

#pragma unroll
  for (int j = 0; j < NPW; ++j) {
    int node = n0 + j;
    if (node >= n) break;

    float2 r0 = g2[(size_t)cA0 * 16 + c];
    float2 r1 = g2[(size_t)cA1 * 16 + c];
    float2 r2 = g2[(size_t)cA2 * 16 + c];
    float2 r3 = g2[(size_t)cA3 * 16 + c];
    float2 rs = g2[(size_t)node * 16 + c];
    float di = dinv[node];

    int n2 = min(node + 2, n - 1);
    int eC = rowptr[n2];
    int endC = rowptr[n2 + 1];

    int lastB = (endB > eB) ? endB - 1 : 0;
    int iB = eB + sub * 4;
    int cB0 = col[min(iB,     lastB)];
    int cB1 = col[min(iB + 1, lastB)];
    int cB2 = col[min(iB + 2, lastB)];
    int cB3 = col[min(iB + 3, lastB)];

    float ax = 0.f, ay = 0.f, az = 0.f, aw = 0.f;
    auto acc2w = [&](float2 raw, float w) {
      float2 f0 = __half22float2(*(const __half2*)&raw.x);
      float2 f1 = __half22float2(*(const __half2*)&raw.y);
      ax = fmaf(w, f0.x, ax); ay = fmaf(w, f0.y, ay);
      az = fmaf(w, f1.x, az); aw = fmaf(w, f1.y, aw);
    };
    acc2w(rs, (lane < 10) ? 1.f : 0.f);  // self-loop
    acc2w(r0, (act && iA     < endA) ? 1.f : 0.f);
    acc2w(r1, (act && iA + 1 < endA) ? 1.f : 0.f);
    acc2w(r2, (act && iA + 2 < endA) ? 1.f : 0.f);
    acc2w(r3, (act && iA + 3 < endA) ? 1.f : 0.f);

    for (int t = eA + 24; t < endA; t += 6) {
      int it = t + sub;
      if (act && it < endA) {
        int sc = col[it];
        acc2w(g2[(size_t)sc * 16 + c], 1.f);
      }
    }

    float bx = __shfl(ax, lane + 30), by = __shfl(ay, lane + 30),
          bz = __shfl(az, lane + 30), bw = __shfl(aw, lane + 30);
    ax += bx; ay += by; az += bz; aw += bw;
    float c1x = __shfl(ax, lane + 10), c1y = __shfl(ay, lane + 10),
          c1z = __shfl(az, lane + 10), c1w = __shfl(aw, lane + 10);
    float c2x = __shfl(ax, lane + 20), c2y = __shfl(ay, lane + 20),
          c2z = __shfl(az, lane + 20), c2w = __shfl(aw, lane + 20);

    if (lane < 10) {
      float sx = ax + c1x + c2x;
      float sy = ay + c1y + c2y;
      float sz = az + c1z + c2z;
      float sw = aw + c1w + c2w;
      float4 bb = ((const float4*)bias)[c];
      float4 o = make_float4(di * sx + bb.x, di * sy + bb.y, di * sz + bb.z,
                             di * sw + bb.w);
      ((float4*)out)[(size_t)node * 10 + c] = o;
    }

    eA = eB; endA = endB; eB = eC; endB = endC;
    iA = eA + sub * 4;
    cA0 = cB0; cA1 = cB1; cA2 = cB2; cA3 = cB3;
  }
}

extern "C" void kernel_launch(void* const* d_in, const int* in_sizes, int n_in,
                              void* d_out, int out_size, void* d_ws, size_t ws_size,
                              hipStream_t stream) {
  const float* x = (const float*)d_in[0];
  const float* W0 = (const float*)d_in[1];
  const float* b0 = (const float*)d_in[2];
  const float* W1 = (const float*)d_in[3];
  const float* b1 = (const float*)d_in[4];
  const float* W2 = (const float*)d_in[5];
  const float* b2 = (const float*)d_in[6];
  const int* ei = (const int*)d_in[7];

  const int N = in_sizes[0] / 128;
  const int E = in_sizes[7] / 2;
  const int* src = ei;
  const int* dst = ei + E;
  const int NB = (N + 255) >> 8;

  char* w = (char*)d_ws;
  size_t off = 0;
  auto alloc = [&](size_t bytes) -> void* {
    void* p = w + off;
    off = (off + bytes + 255) & ~(size_t)255;
    return p;
  };
  int* bucket_cnt = (int*)alloc((size_t)NBMAX * 4);
  float* dinv = (float*)alloc((size_t)N * 4);
  int* rowptr = (int*)alloc((size_t)(N + 1) * 4);
  int* col = (int*)alloc((size_t)E * 4);
  unsigned* bucketbuf = (unsigned*)alloc((size_t)NB * CAP * 4);
  __half* gbuf = (__half*)alloc((size_t)N * 128 * 2);
  __half* hbuf = (__half*)alloc((size_t)N * 128 * 2);
  __half* w0t = (__half*)alloc(128 * 128 * 2);
  __half* w1t = (__half*)alloc(128 * 128 * 2);
  __half* w2t = (__half*)alloc(48 * 128 * 2);
  (void)ws_size;

  hipMemsetAsync(bucket_cnt, 0, (size_t)NBMAX * 4, stream);

  dim3 blk(256);
  dim3 blk128(128);
  int gP1 = (E + 4095) / 4096;
  int gW = (38912 + 255) / 256;
  int gGemm = (N + 127) / 128;
  int gFuse = (N + 31) / 32;   // 2 waves x 16 nodes
  int gAgg = (N + 15) / 16;    // 4 waves x NPW=4 nodes

  // K1: bucket partition + W transpose prep
  bucket_prep_kernel<<<gP1 + gW, blk, 0, stream>>>(src, dst, E, gP1, NB,
                                                   bucket_cnt, bucketbuf,
                                                   W0, W1, W2, w0t, w1t, w2t);
  // K2: CSR build blocks first (latency-bound), then MFMA gemm layer-0
  gemm128_build_kernel<<<gGemm + NB, blk, 0, stream>>>(x, w0t, gbuf, N,
                                                       bucketbuf, bucket_cnt,
                                                       rowptr, dinv, col, N, E, NB);

  // FUSED layer-1: agg(gbuf, weighted, b0, ReLU) -> gemm(w1t, dinv) -> hbuf
  agg_gemm_kernel<true, 8, 128><<<gFuse, blk128, 0, stream>>>(
      gbuf, rowptr, col, dinv, b0, w1t, hbuf, N);
  // FUSED layer-2: agg(hbuf, unweighted, b1, ReLU) -> gemm48(w2t, dinv) -> gbuf
  agg_gemm_kernel<false, 3, 64><<<gFuse, blk128, 0, stream>>>(
      hbuf, rowptr, col, dinv, b1, w2t, gbuf, N);

  aggregate40_kernel<<<gAgg, blk, 0, stream>>>(gbuf, rowptr, col, dinv, b2,
                                               (float*)d_out, N);
}

// Round 13
// 339.613 us; speedup vs baseline: 1.0736x; 1.0736x over previous
//
#include <hip/hip_runtime.h>
#include <hip/hip_fp16.h>

// ---------------------------------------------------------------------------
// GCN 3-layer forward. fp32 accumulate; fp16 message buffer G.
// R4: fp16 G. R11: MFMA fp16 GEMMs, fp16 hbuf, W pre-transposed once.
// R12: bucketed CSR build. R14: cross-node 3-deep agg pipeline (64.5us,
//   at the ~85-outstanding-gathers/CU request-rate cap; proven across 5
//   structures).
// R15 FAILED: wider MLP -> VGPR split. R16 FAILED: stride bug.
// R17: split kernels 342.6us. R18: barrier-free agg+gemm fusion (32 n/wave)
//   -> 337us best; fused dispatch 84.2 = agg(starved 12.2 waves/CU) + gemm.
// R19/R20/R21 FAILED: 16 n/wave variants all 90-92 (B-request tax /
//   occupancy conflict). Fusion never beats full-occupancy agg + serial
//   gemm; its only win is saved launches/round-trips when gemm is BIG.
// R22: HYBRID. fused1 kept (84.2 ~= split1's 84.5, saves hbuf round-trip);
//   layer-2 split back out: agg128 at full occupancy (64.5) + standalone
//   gemm48 (~9) replaces fused2's 84.2. Buffers rotate gbuf->hbuf->gbuf->
//   hbuf. (R12 bench was an infra failure — container died; resubmitted
//   unchanged.)
// ---------------------------------------------------------------------------

#define CAP 8192     // per-bucket capacity (mean 4096, +64 sigma)
#define NBMAX 512

typedef _Float16 f16;
typedef __attribute__((ext_vector_type(8))) _Float16 f16x8;
typedef __attribute__((ext_vector_type(4))) _Float16 f16x4;
typedef __attribute__((ext_vector_type(4))) float f32x4;

// ---------------------------------------------------------------------------
// K1: bucket partition (blocks < gP1) + W fp16-transpose prep (rest).
// Packed entry: (src << 8) | (dst & 255); bucket = dst >> 8.
// ---------------------------------------------------------------------------
__global__ __launch_bounds__(256)
void bucket_prep_kernel(const int* __restrict__ src, const int* __restrict__ dst,
                        int E, int gP1, int NB,
                        int* __restrict__ bucket_cnt, unsigned* __restrict__ bucketbuf,
                        const float* __restrict__ W0, const float* __restrict__ W1,
                        const float* __restrict__ W2,
                        __half* __restrict__ w0t, __half* __restrict__ w1t,
                        __half* __restrict__ w2t) {
  int b = blockIdx.x;
  if (b < gP1) {
    __shared__ int hist[NBMAX];
    __shared__ int cbase[NBMAX];
    int tid = threadIdx.x;
    for (int i = tid; i < NB; i += 256) hist[i] = 0;
    __syncthreads();
    int e0 = b * 4096;
    int eend = min(e0 + 4096, E);
    for (int e = e0 + tid; e < eend; e += 256)
      atomicAdd(&hist[((unsigned)dst[e]) >> 8], 1);
    __syncthreads();
    for (int i = tid; i < NB; i += 256) {
      int h = hist[i];
      cbase[i] = h ? atomicAdd(&bucket_cnt[i], h) : 0;
    }
    __syncthreads();
    for (int i = tid; i < NB; i += 256) hist[i] = 0;
    __syncthreads();
    for (int e = e0 + tid; e < eend; e += 256) {
      int d = dst[e];
      int s = src[e];
      int bk = ((unsigned)d) >> 8;
      int idx = cbase[bk] + atomicAdd(&hist[bk], 1);
      if (idx < CAP)
        bucketbuf[(size_t)bk * CAP + idx] = (((unsigned)s) << 8) | (unsigned)(d & 255);
    }
  } else {
    int i = (b - gP1) * 256 + threadIdx.x;
    if (i < 16384) {
      int n = i >> 7, k = i & 127;
      w0t[i] = __float2half_rn(W0[k * 128 + n]);           // w0t[n][k] = W0[k][n]
    } else if (i < 32768) {
      int j = i - 16384;
      int n = j >> 7, k = j & 127;
      w1t[j] = __float2half_rn(W1[k * 128 + n]);
    } else if (i < 38912) {
      int j = i - 32768;
      int n = j >> 7, k = j & 127;                          // n in [0,48)
      w2t[j] = (n < 40) ? __float2half_rn(W2[k * 40 + n]) : __float2half_rn(0.f);
    }
  }
}

// ---------------------------------------------------------------------------
// Phase 2 (per bucket, fused into K2): counts, scan, rowptr, dinv, col.
// ---------------------------------------------------------------------------
struct P2Shared {
  unsigned plist[CAP];   // 32 KB
  int cnts[256];
  int sm[256];
};

__device__ __forceinline__
void phase2_body(const unsigned* __restrict__ bucketbuf, const int* __restrict__ bucket_cnt,
                 int* __restrict__ rowptr, float* __restrict__ dinv,
                 int* __restrict__ col, int N, int E, int NB, int b, P2Shared& sh) {
  int tid = threadIdx.x;
  int cnt_b = min(bucket_cnt[b], CAP);

  int part = 0;
  for (int i = tid; i < b; i += 256) part += bucket_cnt[i];
  sh.sm[tid] = part;
  __syncthreads();
#pragma unroll
  for (int off = 128; off > 0; off >>= 1) {
    if (tid < off) sh.sm[tid] += sh.sm[tid + off];
    __syncthreads();
  }
  int base = sh.sm[0];
  __syncthreads();

  for (int i = tid; i < cnt_b; i += 256)
    sh.plist[i] = bucketbuf[(size_t)b * CAP + i];
  sh.cnts[tid] = 0;
  __syncthreads();
  for (int i = tid; i < cnt_b; i += 256)
    atomicAdd(&sh.cnts[sh.plist[i] & 255u], 1);
  __syncthreads();

  int myc = sh.cnts[tid];
  sh.sm[tid] = myc;
  __syncthreads();
#pragma unroll
  for (int off = 1; off < 256; off <<= 1) {
    int u = (tid >= off) ? sh.sm[tid - off] : 0;
    __syncthreads();
    sh.sm[tid] += u;
    __syncthreads();
  }
  int exc = sh.sm[tid] - myc;

  int n = (b << 8) + tid;
  if (n < N) {
    rowptr[n] = base + exc;
    dinv[n] = 1.0f / sqrtf((float)myc + 1.0f);
  }
  if (b == NB - 1 && tid == 0) rowptr[N] = E;
  __syncthreads();

  sh.cnts[tid] = base + exc;
  __syncthreads();
  for (int i = tid; i < cnt_b; i += 256) {
    unsigned p = sh.plist[i];
    int pos = atomicAdd(&sh.cnts[p & 255u], 1);
    col[pos] = (int)(p >> 8);
  }
}

// ---------------------------------------------------------------------------
// MFMA fp16 GEMM body (used by K2 for layer-0): G = X @ W, unscaled.
// ---------------------------------------------------------------------------
template <typename TIN, bool SCALE>
__device__ __forceinline__
void mfma_gemm128_body(const TIN* __restrict__ X, const __half* __restrict__ Wt,
                       const float* __restrict__ dinv, __half* __restrict__ G,
                       int nrows, int blk, f16 (*xs)[72], f16 (*ws)[72]) {
  const int tid = threadIdx.x;
  const int wave = tid >> 6;
  const int lane = tid & 63;
  const int mrow = lane & 15;
  const int kg = lane >> 4;
  const int row0 = blk * 128;

  f32x4 acc[2][8];
#pragma unroll
  for (int i = 0; i < 2; ++i)
#pragma unroll
    for (int j = 0; j < 8; ++j) acc[i][j] = (f32x4){0.f, 0.f, 0.f, 0.f};

  for (int k0 = 0; k0 < 128; k0 += 64) {
    if constexpr (sizeof(TIN) == 4) {
#pragma unroll
      for (int t = tid; t < 2048; t += 256) {
        int r = t >> 4;
        int kk = (t & 15) * 4;
        float4 v = make_float4(0.f, 0.f, 0.f, 0.f);
        if (row0 + r < nrows)
          v = *(const float4*)((const float*)X + (size_t)(row0 + r) * 128 + k0 + kk);
        f16x4 hv = {(f16)v.x, (f16)v.y, (f16)v.z, (f16)v.w};
        *(f16x4*)&xs[r][kk] = hv;
      }
    } else {
#pragma unroll
      for (int t = tid; t < 1024; t += 256) {
        int r = t >> 3;
        int kk = (t & 7) * 8;
        f16x8 v = (f16x8){0, 0, 0, 0, 0, 0, 0, 0};
        if (row0 + r < nrows)
          v = *(const f16x8*)((const f16*)X + (size_t)(row0 + r) * 128 + k0 + kk);
        *(f16x8*)&xs[r][kk] = v;
      }
    }
#pragma unroll
    for (int t = tid; t < 1024; t += 256) {
      int r = t >> 3;
      int kk = (t & 7) * 8;
      *(f16x8*)&ws[r][kk] =
          *(const f16x8*)((const f16*)Wt + (size_t)r * 128 + k0 + kk);
    }
    __syncthreads();
#pragma unroll
    for (int ks = 0; ks < 64; ks += 32) {
      f16x8 a0 = *(const f16x8*)&xs[wave * 32 + mrow][ks + kg * 8];
      f16x8 a1 = *(const f16x8*)&xs[wave * 32 + 16 + mrow][ks + kg * 8];
#pragma unroll
      for (int nt = 0; nt < 8; ++nt) {
        f16x8 b = *(const f16x8*)&ws[nt * 16 + mrow][ks + kg * 8];
        acc[0][nt] = __builtin_amdgcn_mfma_f32_16x16x32_f16(a0, b, acc[0][nt], 0, 0, 0);
        acc[1][nt] = __builtin_amdgcn_mfma_f32_16x16x32_f16(a1, b, acc[1][nt], 0, 0, 0);
      }
    }
    __syncthreads();
  }
#pragma unroll
  for (int mt = 0; mt < 2; ++mt) {
    int rbase = row0 + wave * 32 + mt * 16 + kg * 4;
#pragma unroll
    for (int i = 0; i < 4; ++i) {
      int grow = rbase + i;
      if (grow < nrows) {
        float s = SCALE ? dinv[grow] : 1.0f;
        __half* gp = G + (size_t)grow * 128 + mrow;
#pragma unroll
        for (int nt = 0; nt < 8; ++nt)
          gp[nt * 16] = __float2half_rn(s * acc[mt][nt][i]);
      }
    }
  }
}

// Fat K2: blocks [0,NB) build CSR (latency-bound, start first); rest gemm0.
__global__ __launch_bounds__(256)
void gemm128_build_kernel(const float* __restrict__ X, const __half* __restrict__ Wt,
                          __half* __restrict__ G, int nrows,
                          const unsigned* __restrict__ bucketbuf,
                          const int* __restrict__ bucket_cnt,
                          int* __restrict__ rowptr, float* __restrict__ dinv,
                          int* __restrict__ col, int N, int E, int NB) {
  __shared__ char shraw[2 * 128 * 72 * sizeof(f16)];  // 36864 >= sizeof(P2Shared)
  if ((int)blockIdx.x < NB) {
    phase2_body(bucketbuf, bucket_cnt, rowptr, dinv, col, N, E, NB,
                blockIdx.x, *(P2Shared*)shraw);
  } else {
    f16 (*xs)[72] = (f16(*)[72])shraw;
    f16 (*ws)[72] = (f16(*)[72])(shraw + 128 * 72 * sizeof(f16));
    mfma_gemm128_body<float, false>(X, Wt, nullptr, G, nrows, blockIdx.x - NB, xs, ws);
  }
}

// Output layer: N=40 (padded to 48; Wt2 rows 40..47 zero). Pre-scales by dinv.
// G40 row stride = 64 halves (128B-aligned) -> agg40 gathers hit ONE line.
__global__ __launch_bounds__(256)
void mfma_gemm48_kernel(const __half* __restrict__ X, const __half* __restrict__ Wt,
                        const float* __restrict__ dinv, __half* __restrict__ G,
                        int nrows) {
  __shared__ f16 xs[128][72];
  __shared__ f16 ws[48][72];
  const int tid = threadIdx.x;
  const int wave = tid >> 6;
  const int lane = tid & 63;
  const int mrow = lane & 15;
  const int kg = lane >> 4;
  const int row0 = blockIdx.x * 128;

  f32x4 acc[2][3];
#pragma unroll
  for (int i = 0; i < 2; ++i)
#pragma unroll
    for (int j = 0; j < 3; ++j) acc[i][j] = (f32x4){0.f, 0.f, 0.f, 0.f};

  for (int k0 = 0; k0 < 128; k0 += 64) {
#pragma unroll
    for (int t = tid; t < 1024; t += 256) {
      int r = t >> 3;
      int kk = (t & 7) * 8;
      f16x8 v = (f16x8){0, 0, 0, 0, 0, 0, 0, 0};
      if (row0 + r < nrows)
        v = *(const f16x8*)((const f16*)X + (size_t)(row0 + r) * 128 + k0 + kk);
      *(f16x8*)&xs[r][kk] = v;
    }
#pragma unroll
    for (int t = tid; t < 384; t += 256) {
      int r = t >> 3;
      int kk = (t & 7) * 8;
      *(f16x8*)&ws[r][kk] =
          *(const f16x8*)((const f16*)Wt + (size_t)r * 128 + k0 + kk);
    }
    __syncthreads();
#pragma unroll
    for (int ks = 0; ks < 64; ks += 32) {
      f16x8 a0 = *(const f16x8*)&xs[wave * 32 + mrow][ks + kg * 8];
      f16x8 a1 = *(const f16x8*)&xs[wave * 32 + 16 + mrow][ks + kg * 8];
#pragma unroll
      for (int nt = 0; nt < 3; ++nt) {
        f16x8 b = *(const f16x8*)&ws[nt * 16 + mrow][ks + kg * 8];
        acc[0][nt] = __builtin_amdgcn_mfma_f32_16x16x32_f16(a0, b, acc[0][nt], 0, 0, 0);
        acc[1][nt] = __builtin_amdgcn_mfma_f32_16x16x32_f16(a1, b, acc[1][nt], 0, 0, 0);
      }
    }
    __syncthreads();
  }
#pragma unroll
  for (int mt = 0; mt < 2; ++mt) {
    int rbase = row0 + wave * 32 + mt * 16 + kg * 4;
#pragma unroll
    for (int i = 0; i < 4; ++i) {
      int grow = rbase + i;
      if (grow < nrows) {
        float s = dinv[grow];
#pragma unroll
        for (int nt = 0; nt < 3; ++nt) {
          int c = nt * 16 + mrow;
          if (c < 40)
            G[(size_t)grow * 64 + c] = __float2half_rn(s * acc[mt][nt][i]);
        }
      }
    }
  }
}

// ---------------------------------------------------------------------------
// FUSED aggregate + GEMM layer-1 (R18 form, kept): barrier-free, 256-thr
// blocks, 32 nodes/wave. Agg own rows into private LDS slice, then MFMA
// with B direct from global Wt. 84.2us measured = split-equal but saves
// the hbuf round-trip + a launch.
// ---------------------------------------------------------------------------
template <bool WEIGHTED, int NT, int OSTR>
__global__ __launch_bounds__(256, 4)
void agg_gemm_kernel(const __half* __restrict__ G_in, const int* __restrict__ rowptr,
                     const int* __restrict__ col, const float* __restrict__ dinv,
                     const float* __restrict__ bias, const __half* __restrict__ Wt,
                     __half* __restrict__ G_out, int n) {
  __shared__ f16 xs[128][136];
  const int tid = threadIdx.x;
  const int wave = tid >> 6;
  const int lane = tid & 63;
  const int sub = lane >> 4;
  const int c = lane & 15;
  const float4* g4 = (const float4*)G_in;   // row stride = 16 float4

  const int nbase = blockIdx.x * 128;
  const int n0 = nbase + wave * 32;
  if (n0 >= n) return;   // no barriers in this kernel: early-out is safe

  // ---- agg phase: nodes n0 .. n0+31 ----
  int eA = rowptr[n0], endA = rowptr[n0 + 1];
  int nn1 = min(n0 + 1, n - 1);
  int eB = rowptr[nn1], endB = rowptr[nn1 + 1];

  int lastA = (endA > eA) ? endA - 1 : 0;
  int iA = eA + sub;
  int cA0 = col[min(iA,      lastA)];
  int cA1 = col[min(iA + 4,  lastA)];
  int cA2 = col[min(iA + 8,  lastA)];
  int cA3 = col[min(iA + 12, lastA)];
  int cA4 = col[min(iA + 16, lastA)];

  for (int j = 0; j < 32; ++j) {
    int node = n0 + j;
    if (node >= n) break;

    float4 r0 = g4[(size_t)cA0 * 16 + c];
    float4 r1 = g4[(size_t)cA1 * 16 + c];
    float4 r2 = g4[(size_t)cA2 * 16 + c];
    float4 r3 = g4[(size_t)cA3 * 16 + c];
    float4 r4 = g4[(size_t)cA4 * 16 + c];
    float4 rs = g4[(size_t)node * 16 + c];
    float dv0 = 1.f, dv1 = 1.f, dv2 = 1.f, dv3 = 1.f, dv4 = 1.f;
    if (WEIGHTED) {
      dv0 = dinv[cA0]; dv1 = dinv[cA1]; dv2 = dinv[cA2];
      dv3 = dinv[cA3]; dv4 = dinv[cA4];
    }
    float di = dinv[node];

    int n2 = min(node + 2, n - 1);
    int eC = rowptr[n2];
    int endC = rowptr[n2 + 1];

    int lastB = (endB > eB) ? endB - 1 : 0;
    int iB = eB + sub;
    int cB0 = col[min(iB,      lastB)];
    int cB1 = col[min(iB + 4,  lastB)];
    int cB2 = col[min(iB + 8,  lastB)];
    int cB3 = col[min(iB + 12, lastB)];
    int cB4 = col[min(iB + 16, lastB)];

    float a0 = 0.f, a1 = 0.f, a2 = 0.f, a3 = 0.f,
          a4 = 0.f, a5 = 0.f, a6 = 0.f, a7 = 0.f;
    auto accumw = [&](float4 raw, float w) {
      const __half2* h = (const __half2*)&raw;
      float2 f0 = __half22float2(h[0]);
      float2 f1 = __half22float2(h[1]);
      float2 f2 = __half22float2(h[2]);
      float2 f3 = __half22float2(h[3]);
      a0 = fmaf(w, f0.x, a0); a1 = fmaf(w, f0.y, a1);
      a2 = fmaf(w, f1.x, a2); a3 = fmaf(w, f1.y, a3);
      a4 = fmaf(w, f2.x, a4); a5 = fmaf(w, f2.y, a5);
      a6 = fmaf(w, f3.x, a6); a7 = fmaf(w, f3.y, a7);
    };
    accumw(rs, (sub == 0) ? (WEIGHTED ? di : 1.f) : 0.f);  // self-loop
    accumw(r0, (iA      < endA) ? dv0 : 0.f);
    accumw(r1, (iA + 4  < endA) ? dv1 : 0.f);
    accumw(r2, (iA + 8  < endA) ? dv2 : 0.f);
    accumw(r3, (iA + 12 < endA) ? dv3 : 0.f);
    accumw(r4, (iA + 16 < endA) ? dv4 : 0.f);

    for (int t = eA + 20; t < endA; t += 4) {
      int it = t + sub;
      if (it < endA) {
        int sc = col[it];
        accumw(g4[(size_t)sc * 16 + c], WEIGHTED ? dinv[sc] : 1.f);
      }
    }

    a0 += __shfl_xor(a0, 16); a1 += __shfl_xor(a1, 16);
    a2 += __shfl_xor(a2, 16); a3 += __shfl_xor(a3, 16);
    a4 += __shfl_xor(a4, 16); a5 += __shfl_xor(a5, 16);
    a6 += __shfl_xor(a6, 16); a7 += __shfl_xor(a7, 16);
    a0 += __shfl_xor(a0, 32); a1 += __shfl_xor(a1, 32);
    a2 += __shfl_xor(a2, 32); a3 += __shfl_xor(a3, 32);
    a4 += __shfl_xor(a4, 32); a5 += __shfl_xor(a5, 32);
    a6 += __shfl_xor(a6, 32); a7 += __shfl_xor(a7, 32);

    if (sub == 0) {
      const float4* b4 = (const float4*)bias;
      float4 bb0 = b4[c * 2];
      float4 bb1 = b4[c * 2 + 1];
      float o0 = fmaxf(di * a0 + bb0.x, 0.f);
      float o1 = fmaxf(di * a1 + bb0.y, 0.f);
      float o2 = fmaxf(di * a2 + bb0.z, 0.f);
      float o3 = fmaxf(di * a3 + bb0.w, 0.f);
      float o4 = fmaxf(di * a4 + bb1.x, 0.f);
      float o5 = fmaxf(di * a5 + bb1.y, 0.f);
      float o6 = fmaxf(di * a6 + bb1.z, 0.f);
      float o7 = fmaxf(di * a7 + bb1.w, 0.f);
      f16x8 hv = {(f16)o0, (f16)o1, (f16)o2, (f16)o3,
                  (f16)o4, (f16)o5, (f16)o6, (f16)o7};
      *(f16x8*)&xs[wave * 32 + j][c * 8] = hv;
    }

    eA = eB; endA = endB; eB = eC; endB = endC;
    iA = eA + sub;
    cA0 = cB0; cA1 = cB1; cA2 = cB2; cA3 = cB3; cA4 = cB4;
  }

  // ---- gemm phase: own 32 rows x NT 16-col tiles; B direct from global ----
  const int mrow = c;   // lane & 15
  const int kg = sub;   // lane >> 4
  f32x4 acc[2][NT];
#pragma unroll
  for (int i = 0; i < 2; ++i)
#pragma unroll
    for (int j = 0; j < NT; ++j) acc[i][j] = (f32x4){0.f, 0.f, 0.f, 0.f};

#pragma unroll
  for (int ks = 0; ks < 128; ks += 32) {
    f16x8 fa0 = *(const f16x8*)&xs[wave * 32 + mrow][ks + kg * 8];
    f16x8 fa1 = *(const f16x8*)&xs[wave * 32 + 16 + mrow][ks + kg * 8];
#pragma unroll
    for (int nt = 0; nt < NT; ++nt) {
      f16x8 b = *(const f16x8*)((const f16*)Wt +
                                (size_t)(nt * 16 + mrow) * 128 + ks + kg * 8);
      acc[0][nt] = __builtin_amdgcn_mfma_f32_16x16x32_f16(fa0, b, acc[0][nt], 0, 0, 0);
      acc[1][nt] = __builtin_amdgcn_mfma_f32_16x16x32_f16(fa1, b, acc[1][nt], 0, 0, 0);
    }
  }

#pragma unroll
  for (int mt = 0; mt < 2; ++mt) {
    int rbase = n0 + mt * 16 + kg * 4;
#pragma unroll
    for (int i = 0; i < 4; ++i) {
      int grow = rbase + i;
      if (grow < n) {
        float s = dinv[grow];
        __half* gp = G_out + (size_t)grow * OSTR + mrow;
#pragma unroll
        for (int nt = 0; nt < NT; ++nt) {
          if (OSTR == 128 || nt * 16 + mrow < 40)
            gp[nt * 16] = __float2half_rn(s * acc[mt][nt][i]);
        }
      }
    }
  }
}

// ---------------------------------------------------------------------------
// M=128 aggregate (R14 form, full occupancy): cross-node pipeline depth 3,
// 20-edge primary round, weight-0 fma masking. Used for layer-2 agg.
// ---------------------------------------------------------------------------
template <bool RELU, bool WEIGHTED, typename TOUT>
__global__ __launch_bounds__(256)
void aggregate128_kernel(const __half* __restrict__ G, const int* __restrict__ rowptr,
                         const int* __restrict__ col, const float* __restrict__ dinv,
                         const float* __restrict__ bias, TOUT* __restrict__ out,
                         int n) {
  constexpr int NPW = 4;
  int wid = threadIdx.x >> 6;
  int lane = threadIdx.x & 63;
  int n0 = (blockIdx.x * 4 + wid) * NPW;
  if (n0 >= n) return;

  int sub = lane >> 4;
  int c = lane & 15;
  const float4* g4 = (const float4*)G;  // row stride = 16 float4

  int eA = rowptr[n0], endA = rowptr[n0 + 1];
  int n1 = min(n0 + 1, n - 1);
  int eB = rowptr[n1], endB = rowptr[n1 + 1];

  int lastA = (endA > eA) ? endA - 1 : 0;
  int iA = eA + sub;
  int cA0 = col[min(iA,      lastA)];
  int cA1 = col[min(iA + 4,  lastA)];
  int cA2 = col[min(iA + 8,  lastA)];
  int cA3 = col[min(iA + 12, lastA)];
  int cA4 = col[min(iA + 16, lastA)];

#pragma unroll
  for (int j = 0; j < NPW; ++j) {
    int node = n0 + j;
    if (node >= n) break;

    float4 r0 = g4[(size_t)cA0 * 16 + c];
    float4 r1 = g4[(size_t)cA1 * 16 + c];
    float4 r2 = g4[(size_t)cA2 * 16 + c];
    float4 r3 = g4[(size_t)cA3 * 16 + c];
    float4 r4 = g4[(size_t)cA4 * 16 + c];
    float4 rs = g4[(size_t)node * 16 + c];
    float dv0 = 1.f, dv1 = 1.f, dv2 = 1.f, dv3 = 1.f, dv4 = 1.f;
    if (WEIGHTED) {
      dv0 = dinv[cA0]; dv1 = dinv[cA1]; dv2 = dinv[cA2];
      dv3 = dinv[cA3]; dv4 = dinv[cA4];
    }
    float di = dinv[node];

    int n2 = min(node + 2, n - 1);
    int eC = rowptr[n2];
    int endC = rowptr[n2 + 1];

    int lastB = (endB > eB) ? endB - 1 : 0;
    int iB = eB + sub;
    int cB0 = col[min(iB,      lastB)];
    int cB1 = col[min(iB + 4,  lastB)];
    int cB2 = col[min(iB + 8,  lastB)];
    int cB3 = col[min(iB + 12, lastB)];
    int cB4 = col[min(iB + 16, lastB)];

    float a0 = 0.f, a1 = 0.f, a2 = 0.f, a3 = 0.f,
          a4 = 0.f, a5 = 0.f, a6 = 0.f, a7 = 0.f;
    auto accumw = [&](float4 raw, float w) {
      const __half2* h = (const __half2*)&raw;
      float2 f0 = __half22float2(h[0]);
      float2 f1 = __half22float2(h[1]);
      float2 f2 = __half22float2(h[2]);
      float2 f3 = __half22float2(h[3]);
      a0 = fmaf(w, f0.x, a0); a1 = fmaf(w, f0.y, a1);
      a2 = fmaf(w, f1.x, a2); a3 = fmaf(w, f1.y, a3);
      a4 = fmaf(w, f2.x, a4); a5 = fmaf(w, f2.y, a5);
      a6 = fmaf(w, f3.x, a6); a7 = fmaf(w, f3.y, a7);
    };
    accumw(rs, (sub == 0) ? (WEIGHTED ? di : 1.f) : 0.f);  // self-loop
    accumw(r0, (iA      < endA) ? dv0 : 0.f);
    accumw(r1, (iA + 4  < endA) ? dv1 : 0.f);
    accumw(r2, (iA + 8  < endA) ? dv2 : 0.f);
    accumw(r3, (iA + 12 < endA) ? dv3 : 0.f);
    accumw(r4, (iA + 16 < endA) ? dv4 : 0.f);

    for (int t = eA + 20; t < endA; t += 4) {
      int it = t + sub;
      if (it < endA) {
        int sc = col[it];
        accumw(g4[(size_t)sc * 16 + c], WEIGHTED ? dinv[sc] : 1.f);
      }
    }

    a0 += __shfl_xor(a0, 16); a1 += __shfl_xor(a1, 16);
    a2 += __shfl_xor(a2, 16); a3 += __shfl_xor(a3, 16);
    a4 += __shfl_xor(a4, 16); a5 += __shfl_xor(a5, 16);
    a6 += __shfl_xor(a6, 16); a7 += __shfl_xor(a7, 16);
    a0 += __shfl_xor(a0, 32); a1 += __shfl_xor(a1, 32);
    a2 += __shfl_xor(a2, 32); a3 += __shfl_xor(a3, 32);
    a4 += __shfl_xor(a4, 32); a5 += __shfl_xor(a5, 32);
    a6 += __shfl_xor(a6, 32); a7 += __shfl_xor(a7, 32);

    if (sub == 0) {
      const float4* b4 = (const float4*)bias;
      float4 bb0 = b4[c * 2];
      float4 bb1 = b4[c * 2 + 1];
      float o[8] = {di * a0 + bb0.x, di * a1 + bb0.y, di * a2 + bb0.z,
                    di * a3 + bb0.w, di * a4 + bb1.x, di * a5 + bb1.y,
                    di * a6 + bb1.z, di * a7 + bb1.w};
      if (RELU) {
#pragma unroll
        for (int k = 0; k < 8; ++k) o[k] = fmaxf(o[k], 0.f);
      }
      if constexpr (sizeof(TOUT) == 2) {
        union { __half2 h[4]; float4 f; } u;
        u.h[0] = __floats2half2_rn(o[0], o[1]);
        u.h[1] = __floats2half2_rn(o[2], o[3]);
        u.h[2] = __floats2half2_rn(o[4], o[5]);
        u.h[3] = __floats2half2_rn(o[6], o[7]);
        *(float4*)((__half*)out + (size_t)node * 128 + c * 8) = u.f;
      } else {
        float4* op = (float4*)((float*)out + (size_t)node * 128 + c * 8);
        op[0] = make_float4(o[0], o[1], o[2], o[3]);
        op[1] = make_float4(o[4], o[5], o[6], o[7]);
      }
    }

    eA = eB; endA = endB; eB = eC; endB = endC;
    iA = eA + sub;
    cA0 = cB0; cA1 = cB1; cA2 = cB2; cA3 = cB3; cA4 = cB4;
  }
}

// M=40 aggregate (unweighted: G pre-scaled), R14 form. G40 rows at 128B
// stride = 16 float2 per row -> one aligned line per gather.
__global__ __launch_bounds__(256)
void aggregate40_kernel(const __half* __restrict__ G, const int* __restrict__ rowptr,
                        const int* __restrict__ col, const float* __restrict__ dinv,
                        const float* __restrict__ bias, float* __restrict__ out,
                        int n) {
  constexpr int NPW = 4;
  int wid = threadIdx.x >> 6;
  int lane = threadIdx.x & 63;
  int n0 = (blockIdx.x * 4 + wid) * NPW;
  if (n0 >= n) return;

  int sub = lane / 10;    // 0..6 (6 = idle)
  int c = lane % 10;
  bool act = sub < 6;
  const float2* g2 = (const float2*)G;   // row stride = 16 float2 (128B)

  int eA = rowptr[n0], endA = rowptr[n0 + 1];
  int n1 = min(n0 + 1, n - 1);
  int eB = rowptr[n1], endB = rowptr[n1 + 1];

  int lastA = (endA > eA) ? endA - 1 : 0;
  int iA = eA + sub * 4;
  int cA0 = col[min(iA,     lastA)];
  int cA1 = col[min(iA + 1, lastA)];
  int cA2 = col[min(iA + 2, lastA)];
  int cA3 = col[min(iA + 3, lastA)];

#pragma unroll
  for (int j = 0; j < NPW; ++j) {
    int node = n0 + j;
    if (node >= n) break;

    float2 r0 = g2[(size_t)cA0 * 16 + c];
    float2 r1 = g2[(size_t)cA1 * 16 + c];
    float2 r2 = g2[(size_t)cA2 * 16 + c];
    float2 r3 = g2[(size_t)cA3 * 16 + c];
    float2 rs = g2[(size_t)node * 16 + c];
    float di = dinv[node];

    int n2 = min(node + 2, n - 1);
    int eC = rowptr[n2];
    int endC = rowptr[n2 + 1];

    int lastB = (endB > eB) ? endB - 1 : 0;
    int iB = eB + sub * 4;
    int cB0 = col[min(iB,     lastB)];
    int cB1 = col[min(iB + 1, lastB)];
    int cB2 = col[min(iB + 2, lastB)];
    int cB3 = col[min(iB + 3, lastB)];

    float ax = 0.f, ay = 0.f, az = 0.f, aw = 0.f;
    auto acc2w = [&](float2 raw, float w) {
      float2 f0 = __half22float2(*(const __half2*)&raw.x);
      float2 f1 = __half22float2(*(const __half2*)&raw.y);
      ax = fmaf(w, f0.x, ax); ay = fmaf(w, f0.y, ay);
      az = fmaf(w, f1.x, az); aw = fmaf(w, f1.y, aw);
    };
    acc2w(rs, (lane < 10) ? 1.f : 0.f);  // self-loop
    acc2w(r0, (act && iA     < endA) ? 1.f : 0.f);
    acc2w(r1, (act && iA + 1 < endA) ? 1.f : 0.f);
    acc2w(r2, (act && iA + 2 < endA) ? 1.f : 0.f);
    acc2w(r3, (act && iA + 3 < endA) ? 1.f : 0.f);

    for (int t = eA + 24; t < endA; t += 6) {
      int it = t + sub;
      if (act && it < endA) {
        int sc = col[it];
        acc2w(g2[(size_t)sc * 16 + c], 1.f);
      }
    }

    float bx = __shfl(ax, lane + 30), by = __shfl(ay, lane + 30),
          bz = __shfl(az, lane + 30), bw = __shfl(aw, lane + 30);
    ax += bx; ay += by; az += bz; aw += bw;
    float c1x = __shfl(ax, lane + 10), c1y = __shfl(ay, lane + 10),
          c1z = __shfl(az, lane + 10), c1w = __shfl(aw, lane + 10);
    float c2x = __shfl(ax, lane + 20), c2y = __shfl(ay, lane + 20),
          c2z = __shfl(az, lane + 20), c2w = __shfl(aw, lane + 20);

    if (lane < 10) {
      float sx = ax + c1x + c2x;
      float sy = ay + c1y + c2y;
      float sz = az + c1z + c2z;
      float sw = aw + c1w + c2w;
      float4 bb = ((const float4*)bias)[c];
      float4 o = make_float4(di * sx + bb.x, di * sy + bb.y, di * sz + bb.z,
                             di * sw + bb.w);
      ((float4*)out)[(size_t)node * 10 + c] = o;
    }

    eA = eB; endA = endB; eB = eC; endB = endC;
    iA = eA + sub * 4;
    cA0 = cB0; cA1 = cB1; cA2 = cB2; cA3 = cB3;
  }
}

extern "C" void kernel_launch(void* const* d_in, const int* in_sizes, int n_in,
                              void* d_out, int out_size, void* d_ws, size_t ws_size,
                              hipStream_t stream) {
  const float* x = (const float*)d_in[0];
  const float* W0 = (const float*)d_in[1];
  const float* b0 = (const float*)d_in[2];
  const float* W1 = (const float*)d_in[3];
  const float* b1 = (const float*)d_in[4];
  const float* W2 = (const float*)d_in[5];
  const float* b2 = (const float*)d_in[6];
  const int* ei = (const int*)d_in[7];

  const int N = in_sizes[0] / 128;
  const int E = in_sizes[7] / 2;
  const int* src = ei;
  const int* dst = ei + E;
  const int NB = (N + 255) >> 8;

  char* w = (char*)d_ws;
  size_t off = 0;
  auto alloc = [&](size_t bytes) -> void* {
    void* p = w + off;
    off = (off + bytes + 255) & ~(size_t)255;
    return p;
  };
  int* bucket_cnt = (int*)alloc((size_t)NBMAX * 4);
  float* dinv = (float*)alloc((size_t)N * 4);
  int* rowptr = (int*)alloc((size_t)(N + 1) * 4);
  int* col = (int*)alloc((size_t)E * 4);
  unsigned* bucketbuf = (unsigned*)alloc((size_t)NB * CAP * 4);
  __half* gbuf = (__half*)alloc((size_t)N * 128 * 2);
  __half* hbuf = (__half*)alloc((size_t)N * 128 * 2);
  __half* w0t = (__half*)alloc(128 * 128 * 2);
  __half* w1t = (__half*)alloc(128 * 128 * 2);
  __half* w2t = (__half*)alloc(48 * 128 * 2);
  (void)ws_size;

  hipMemsetAsync(bucket_cnt, 0, (size_t)NBMAX * 4, stream);

  dim3 blk(256);
  int gP1 = (E + 4095) / 4096;
  int gW = (38912 + 255) / 256;
  int gGemm = (N + 127) / 128;
  int gAgg = (N + 15) / 16;    // 4 waves x NPW=4 nodes

  // K1: bucket partition + W transpose prep
  bucket_prep_kernel<<<gP1 + gW, blk, 0, stream>>>(src, dst, E, gP1, NB,
                                                   bucket_cnt, bucketbuf,
                                                   W0, W1, W2, w0t, w1t, w2t);
  // K2: CSR build blocks first (latency-bound), then MFMA gemm layer-0
  gemm128_build_kernel<<<gGemm + NB, blk, 0, stream>>>(x, w0t, gbuf, N,
                                                       bucketbuf, bucket_cnt,
                                                       rowptr, dinv, col, N, E, NB);

  // FUSED layer-1 (R18): agg(gbuf, weighted, b0, ReLU) -> gemm(w1t, dinv) -> hbuf
  agg_gemm_kernel<true, 8, 128><<<gGemm, blk, 0, stream>>>(
      gbuf, rowptr, col, dinv, b0, w1t, hbuf, N);

  // SPLIT layer-2: agg128 at full occupancy, then standalone gemm48
  aggregate128_kernel<true, false, __half><<<gAgg, blk, 0, stream>>>(
      hbuf, rowptr, col, dinv, b1, gbuf, N);
  mfma_gemm48_kernel<<<gGemm, blk, 0, stream>>>(gbuf, w2t, dinv, hbuf, N);

  aggregate40_kernel<<<gAgg, blk, 0, stream>>>(hbuf, rowptr, col, dinv, b2,
                                               (float*)d_out, N);
}

// Round 14
// 334.544 us; speedup vs baseline: 1.0899x; 1.0152x over previous
//
#include <hip/hip_runtime.h>
#include <hip/hip_fp16.h>

// ---------------------------------------------------------------------------
// GCN 3-layer forward. fp32 accumulate; fp16 message buffer G.
// R4: fp16 G. R11: MFMA fp16 GEMMs, fp16 hbuf, W pre-transposed once.
// R12: bucketed CSR build. R14: cross-node 3-deep agg pipeline (64.5us, at
//   the ~85-outstanding-gathers/CU request-rate cap; proven across 6
//   structures). R15/R16/R19/R20/R21 FAILED (journal). R17: split 342.6.
// R18: barrier-free agg+gemm fusion (32 n/wave, 256-thr) -> 337.1us BEST.
// R22: layer-2 split test -> 339.6 (= fused2 within noise; extra launch gap
//   cancels the agg-occupancy gain). CONCLUSION: R18 pipeline is optimal
//   arrangement; all aggregates at request cap, FETCH at 8-XCD floor.
// R23 (this round): revert to R18 pipeline + single-pass K1 (stage packed
//   edge + bucket id in LDS on first read; histogram/reserve/scatter from
//   LDS -> saves the 6.4MB dst re-read and the 2nd global-load chain).
// ---------------------------------------------------------------------------

#define CAP 8192     // per-bucket capacity (mean 4096, +64 sigma)
#define NBMAX 512

typedef _Float16 f16;
typedef __attribute__((ext_vector_type(8))) _Float16 f16x8;
typedef __attribute__((ext_vector_type(4))) _Float16 f16x4;
typedef __attribute__((ext_vector_type(4))) float f32x4;

// ---------------------------------------------------------------------------
// K1: bucket partition (blocks < gP1, single-pass LDS-staged) + W fp16-
// transpose prep (rest). Packed entry: (src << 8) | (dst & 255).
// ---------------------------------------------------------------------------
__global__ __launch_bounds__(256)
void bucket_prep_kernel(const int* __restrict__ src, const int* __restrict__ dst,
                        int E, int gP1, int NB,
                        int* __restrict__ bucket_cnt, unsigned* __restrict__ bucketbuf,
                        const float* __restrict__ W0, const float* __restrict__ W1,
                        const float* __restrict__ W2,
                        __half* __restrict__ w0t, __half* __restrict__ w1t,
                        __half* __restrict__ w2t) {
  int b = blockIdx.x;
  if (b < gP1) {
    __shared__ unsigned pk[4096];      // 16 KB packed entries
    __shared__ unsigned short bks[4096];  // 8 KB bucket ids
    __shared__ int hist[NBMAX];
    __shared__ int cbase[NBMAX];
    int tid = threadIdx.x;
    for (int i = tid; i < NB; i += 256) hist[i] = 0;
    __syncthreads();
    int e0 = b * 4096;
    int eend = min(e0 + 4096, E);
    int cnt = eend - e0;
    // single global read of (dst, src): stage packed + bucket id in LDS
    for (int i = tid; i < cnt; i += 256) {
      int d = dst[e0 + i];
      int s = src[e0 + i];
      int bk = ((unsigned)d) >> 8;
      pk[i] = (((unsigned)s) << 8) | (unsigned)(d & 255);
      bks[i] = (unsigned short)bk;
      atomicAdd(&hist[bk], 1);
    }
    __syncthreads();
    for (int i = tid; i < NB; i += 256) {
      int h = hist[i];
      cbase[i] = h ? atomicAdd(&bucket_cnt[i], h) : 0;
    }
    __syncthreads();
    for (int i = tid; i < NB; i += 256) hist[i] = 0;
    __syncthreads();
    // scatter from LDS (no second global read)
    for (int i = tid; i < cnt; i += 256) {
      int bk = bks[i];
      int idx = cbase[bk] + atomicAdd(&hist[bk], 1);
      if (idx < CAP)
        bucketbuf[(size_t)bk * CAP + idx] = pk[i];
    }
  } else {
    int i = (b - gP1) * 256 + threadIdx.x;
    if (i < 16384) {
      int n = i >> 7, k = i & 127;
      w0t[i] = __float2half_rn(W0[k * 128 + n]);           // w0t[n][k] = W0[k][n]
    } else if (i < 32768) {
      int j = i - 16384;
      int n = j >> 7, k = j & 127;
      w1t[j] = __float2half_rn(W1[k * 128 + n]);
    } else if (i < 38912) {
      int j = i - 32768;
      int n = j >> 7, k = j & 127;                          // n in [0,48)
      w2t[j] = (n < 40) ? __float2half_rn(W2[k * 40 + n]) : __float2half_rn(0.f);
    }
  }
}

// ---------------------------------------------------------------------------
// Phase 2 (per bucket, fused into K2): counts, scan, rowptr, dinv, col.
// ---------------------------------------------------------------------------
struct P2Shared {
  unsigned plist[CAP];   // 32 KB
  int cnts[256];
  int sm[256];
};

__device__ __forceinline__
void phase2_body(const unsigned* __restrict__ bucketbuf, const int* __restrict__ bucket_cnt,
                 int* __restrict__ rowptr, float* __restrict__ dinv,
                 int* __restrict__ col, int N, int E, int NB, int b, P2Shared& sh) {
  int tid = threadIdx.x;
  int cnt_b = min(bucket_cnt[b], CAP);

  int part = 0;
  for (int i = tid; i < b; i += 256) part += bucket_cnt[i];
  sh.sm[tid] = part;
  __syncthreads();
#pragma unroll
  for (int off = 128; off > 0; off >>= 1) {
    if (tid < off) sh.sm[tid] += sh.sm[tid + off];
    __syncthreads();
  }
  int base = sh.sm[0];
  __syncthreads();

  for (int i = tid; i < cnt_b; i += 256)
    sh.plist[i] = bucketbuf[(size_t)b * CAP + i];
  sh.cnts[tid] = 0;
  __syncthreads();
  for (int i = tid; i < cnt_b; i += 256)
    atomicAdd(&sh.cnts[sh.plist[i] & 255u], 1);
  __syncthreads();

  int myc = sh.cnts[tid];
  sh.sm[tid] = myc;
  __syncthreads();
#pragma unroll
  for (int off = 1; off < 256; off <<= 1) {
    int u = (tid >= off) ? sh.sm[tid - off] : 0;
    __syncthreads();
    sh.sm[tid] += u;
    __syncthreads();
  }
  int exc = sh.sm[tid] - myc;

  int n = (b << 8) + tid;
  if (n < N) {
    rowptr[n] = base + exc;
    dinv[n] = 1.0f / sqrtf((float)myc + 1.0f);
  }
  if (b == NB - 1 && tid == 0) rowptr[N] = E;
  __syncthreads();

  sh.cnts[tid] = base + exc;
  __syncthreads();
  for (int i = tid; i < cnt_b; i += 256) {
    unsigned p = sh.plist[i];
    int pos = atomicAdd(&sh.cnts[p & 255u], 1);
    col[pos] = (int)(p >> 8);
  }
}

// ---------------------------------------------------------------------------
// MFMA fp16 GEMM body (used by K2 for layer-0): G = X @ W, unscaled.
// ---------------------------------------------------------------------------
template <typename TIN, bool SCALE>
__device__ __forceinline__
void mfma_gemm128_body(const TIN* __restrict__ X, const __half* __restrict__ Wt,
                       const float* __restrict__ dinv, __half* __restrict__ G,
                       int nrows, int blk, f16 (*xs)[72], f16 (*ws)[72]) {
  const int tid = threadIdx.x;
  const int wave = tid >> 6;
  const int lane = tid & 63;
  const int mrow = lane & 15;
  const int kg = lane >> 4;
  const int row0 = blk * 128;

  f32x4 acc[2][8];
#pragma unroll
  for (int i = 0; i < 2; ++i)
#pragma unroll
    for (int j = 0; j < 8; ++j) acc[i][j] = (f32x4){0.f, 0.f, 0.f, 0.f};

  for (int k0 = 0; k0 < 128; k0 += 64) {
    if constexpr (sizeof(TIN) == 4) {
#pragma unroll
      for (int t = tid; t < 2048; t += 256) {
        int r = t >> 4;
        int kk = (t & 15) * 4;
        float4 v = make_float4(0.f, 0.f, 0.f, 0.f);
        if (row0 + r < nrows)
          v = *(const float4*)((const float*)X + (size_t)(row0 + r) * 128 + k0 + kk);
        f16x4 hv = {(f16)v.x, (f16)v.y, (f16)v.z, (f16)v.w};
        *(f16x4*)&xs[r][kk] = hv;
      }
    } else {
#pragma unroll
      for (int t = tid; t < 1024; t += 256) {
        int r = t >> 3;
        int kk = (t & 7) * 8;
        f16x8 v = (f16x8){0, 0, 0, 0, 0, 0, 0, 0};
        if (row0 + r < nrows)
          v = *(const f16x8*)((const f16*)X + (size_t)(row0 + r) * 128 + k0 + kk);
        *(f16x8*)&xs[r][kk] = v;
      }
    }
#pragma unroll
    for (int t = tid; t < 1024; t += 256) {
      int r = t >> 3;
      int kk = (t & 7) * 8;
      *(f16x8*)&ws[r][kk] =
          *(const f16x8*)((const f16*)Wt + (size_t)r * 128 + k0 + kk);
    }
    __syncthreads();
#pragma unroll
    for (int ks = 0; ks < 64; ks += 32) {
      f16x8 a0 = *(const f16x8*)&xs[wave * 32 + mrow][ks + kg * 8];
      f16x8 a1 = *(const f16x8*)&xs[wave * 32 + 16 + mrow][ks + kg * 8];
#pragma unroll
      for (int nt = 0; nt < 8; ++nt) {
        f16x8 b = *(const f16x8*)&ws[nt * 16 + mrow][ks + kg * 8];
        acc[0][nt] = __builtin_amdgcn_mfma_f32_16x16x32_f16(a0, b, acc[0][nt], 0, 0, 0);
        acc[1][nt] = __builtin_amdgcn_mfma_f32_16x16x32_f16(a1, b, acc[1][nt], 0, 0, 0);
      }
    }
    __syncthreads();
  }
#pragma unroll
  for (int mt = 0; mt < 2; ++mt) {
    int rbase = row0 + wave * 32 + mt * 16 + kg * 4;
#pragma unroll
    for (int i = 0; i < 4; ++i) {
      int grow = rbase + i;
      if (grow < nrows) {
        float s = SCALE ? dinv[grow] : 1.0f;
        __half* gp = G + (size_t)grow * 128 + mrow;
#pragma unroll
        for (int nt = 0; nt < 8; ++nt)
          gp[nt * 16] = __float2half_rn(s * acc[mt][nt][i]);
      }
    }
  }
}

// Fat K2: blocks [0,NB) build CSR (latency-bound, start first); rest gemm0.
__global__ __launch_bounds__(256)
void gemm128_build_kernel(const float* __restrict__ X, const __half* __restrict__ Wt,
                          __half* __restrict__ G, int nrows,
                          const unsigned* __restrict__ bucketbuf,
                          const int* __restrict__ bucket_cnt,
                          int* __restrict__ rowptr, float* __restrict__ dinv,
                          int* __restrict__ col, int N, int E, int NB) {
  __shared__ char shraw[2 * 128 * 72 * sizeof(f16)];  // 36864 >= sizeof(P2Shared)
  if ((int)blockIdx.x < NB) {
    phase2_body(bucketbuf, bucket_cnt, rowptr, dinv, col, N, E, NB,
                blockIdx.x, *(P2Shared*)shraw);
  } else {
    f16 (*xs)[72] = (f16(*)[72])shraw;
    f16 (*ws)[72] = (f16(*)[72])(shraw + 128 * 72 * sizeof(f16));
    mfma_gemm128_body<float, false>(X, Wt, nullptr, G, nrows, blockIdx.x - NB, xs, ws);
  }
}

// ---------------------------------------------------------------------------
// FUSED aggregate + GEMM (R18 form): barrier-free, 256-thr blocks, 32
// nodes/wave. Each wave aggregates its own 32 rows (R14 3-deep pipeline,
// 20-edge rounds, weight-0 fma masking) with bias+ReLU into its private LDS
// slice, then MFMAs them (A = own LDS rows, no syncthreads; B direct from
// global Wt, L1/L2-resident). Epilogue scales by dinv[row] -> G_out (OSTR).
// NT=8/OSTR=128 for layer-1; NT=3/OSTR=64 for layer-2 (G40, 128B rows).
// ---------------------------------------------------------------------------
template <bool WEIGHTED, int NT, int OSTR>
__global__ __launch_bounds__(256, 4)
void agg_gemm_kernel(const __half* __restrict__ G_in, const int* __restrict__ rowptr,
                     const int* __restrict__ col, const float* __restrict__ dinv,
                     const float* __restrict__ bias, const __half* __restrict__ Wt,
                     __half* __restrict__ G_out, int n) {
  __shared__ f16 xs[128][136];
  const int tid = threadIdx.x;
  const int wave = tid >> 6;
  const int lane = tid & 63;
  const int sub = lane >> 4;
  const int c = lane & 15;
  const float4* g4 = (const float4*)G_in;   // row stride = 16 float4

  const int nbase = blockIdx.x * 128;
  const int n0 = nbase + wave * 32;
  if (n0 >= n) return;   // no barriers in this kernel: early-out is safe

  // ---- agg phase: nodes n0 .. n0+31 ----
  int eA = rowptr[n0], endA = rowptr[n0 + 1];
  int nn1 = min(n0 + 1, n - 1);
  int eB = rowptr[nn1], endB = rowptr[nn1 + 1];

  int lastA = (endA > eA) ? endA - 1 : 0;
  int iA = eA + sub;
  int cA0 = col[min(iA,      lastA)];
  int cA1 = col[min(iA + 4,  lastA)];
  int cA2 = col[min(iA + 8,  lastA)];
  int cA3 = col[min(iA + 12, lastA)];
  int cA4 = col[min(iA + 16, lastA)];

  for (int j = 0; j < 32; ++j) {
    int node = n0 + j;
    if (node >= n) break;

    float4 r0 = g4[(size_t)cA0 * 16 + c];
    float4 r1 = g4[(size_t)cA1 * 16 + c];
    float4 r2 = g4[(size_t)cA2 * 16 + c];
    float4 r3 = g4[(size_t)cA3 * 16 + c];
    float4 r4 = g4[(size_t)cA4 * 16 + c];
    float4 rs = g4[(size_t)node * 16 + c];
    float dv0 = 1.f, dv1 = 1.f, dv2 = 1.f, dv3 = 1.f, dv4 = 1.f;
    if (WEIGHTED) {
      dv0 = dinv[cA0]; dv1 = dinv[cA1]; dv2 = dinv[cA2];
      dv3 = dinv[cA3]; dv4 = dinv[cA4];
    }
    float di = dinv[node];

    int n2 = min(node + 2, n - 1);
    int eC = rowptr[n2];
    int endC = rowptr[n2 + 1];

    int lastB = (endB > eB) ? endB - 1 : 0;
    int iB = eB + sub;
    int cB0 = col[min(iB,      lastB)];
    int cB1 = col[min(iB + 4,  lastB)];
    int cB2 = col[min(iB + 8,  lastB)];
    int cB3 = col[min(iB + 12, lastB)];
    int cB4 = col[min(iB + 16, lastB)];

    float a0 = 0.f, a1 = 0.f, a2 = 0.f, a3 = 0.f,
          a4 = 0.f, a5 = 0.f, a6 = 0.f, a7 = 0.f;
    auto accumw = [&](float4 raw, float w) {
      const __half2* h = (const __half2*)&raw;
      float2 f0 = __half22float2(h[0]);
      float2 f1 = __half22float2(h[1]);
      float2 f2 = __half22float2(h[2]);
      float2 f3 = __half22float2(h[3]);
      a0 = fmaf(w, f0.x, a0); a1 = fmaf(w, f0.y, a1);
      a2 = fmaf(w, f1.x, a2); a3 = fmaf(w, f1.y, a3);
      a4 = fmaf(w, f2.x, a4); a5 = fmaf(w, f2.y, a5);
      a6 = fmaf(w, f3.x, a6); a7 = fmaf(w, f3.y, a7);
    };
    accumw(rs, (sub == 0) ? (WEIGHTED ? di : 1.f) : 0.f);  // self-loop
    accumw(r0, (iA      < endA) ? dv0 : 0.f);
    accumw(r1, (iA + 4  < endA) ? dv1 : 0.f);
    accumw(r2, (iA + 8  < endA) ? dv2 : 0.f);
    accumw(r3, (iA + 12 < endA) ? dv3 : 0.f);
    accumw(r4, (iA + 16 < endA) ? dv4 : 0.f);

    for (int t = eA + 20; t < endA; t += 4) {
      int it = t + sub;
      if (it < endA) {
        int sc = col[it];
        accumw(g4[(size_t)sc * 16 + c], WEIGHTED ? dinv[sc] : 1.f);
      }
    }

    a0 += __shfl_xor(a0, 16); a1 += __shfl_xor(a1, 16);
    a2 += __shfl_xor(a2, 16); a3 += __shfl_xor(a3, 16);
    a4 += __shfl_xor(a4, 16); a5 += __shfl_xor(a5, 16);
    a6 += __shfl_xor(a6, 16); a7 += __shfl_xor(a7, 16);
    a0 += __shfl_xor(a0, 32); a1 += __shfl_xor(a1, 32);
    a2 += __shfl_xor(a2, 32); a3 += __shfl_xor(a3, 32);
    a4 += __shfl_xor(a4, 32); a5 += __shfl_xor(a5, 32);
    a6 += __shfl_xor(a6, 32); a7 += __shfl_xor(a7, 32);

    if (sub == 0) {
      const float4* b4 = (const float4*)bias;
      float4 bb0 = b4[c * 2];
      float4 bb1 = b4[c * 2 + 1];
      float o0 = fmaxf(di * a0 + bb0.x, 0.f);
      float o1 = fmaxf(di * a1 + bb0.y, 0.f);
      float o2 = fmaxf(di * a2 + bb0.z, 0.f);
      float o3 = fmaxf(di * a3 + bb0.w, 0.f);
      float o4 = fmaxf(di * a4 + bb1.x, 0.f);
      float o5 = fmaxf(di * a5 + bb1.y, 0.f);
      float o6 = fmaxf(di * a6 + bb1.z, 0.f);
      float o7 = fmaxf(di * a7 + bb1.w, 0.f);
      f16x8 hv = {(f16)o0, (f16)o1, (f16)o2, (f16)o3,
                  (f16)o4, (f16)o5, (f16)o6, (f16)o7};
      *(f16x8*)&xs[wave * 32 + j][c * 8] = hv;
    }

    eA = eB; endA = endB; eB = eC; endB = endC;
    iA = eA + sub;
    cA0 = cB0; cA1 = cB1; cA2 = cB2; cA3 = cB3; cA4 = cB4;
  }

  // ---- gemm phase: own 32 rows x NT 16-col tiles; B direct from global ----
  const int mrow = c;   // lane & 15
  const int kg = sub;   // lane >> 4
  f32x4 acc[2][NT];
#pragma unroll
  for (int i = 0; i < 2; ++i)
#pragma unroll
    for (int j = 0; j < NT; ++j) acc[i][j] = (f32x4){0.f, 0.f, 0.f, 0.f};

#pragma unroll
  for (int ks = 0; ks < 128; ks += 32) {
    f16x8 fa0 = *(const f16x8*)&xs[wave * 32 + mrow][ks + kg * 8];
    f16x8 fa1 = *(const f16x8*)&xs[wave * 32 + 16 + mrow][ks + kg * 8];
#pragma unroll
    for (int nt = 0; nt < NT; ++nt) {
      f16x8 b = *(const f16x8*)((const f16*)Wt +
                                (size_t)(nt * 16 + mrow) * 128 + ks + kg * 8);
      acc[0][nt] = __builtin_amdgcn_mfma_f32_16x16x32_f16(fa0, b, acc[0][nt], 0, 0, 0);
      acc[1][nt] = __builtin_amdgcn_mfma_f32_16x16x32_f16(fa1, b, acc[1][nt], 0, 0, 0);
    }
  }

#pragma unroll
  for (int mt = 0; mt < 2; ++mt) {
    int rbase = n0 + mt * 16 + kg * 4;
#pragma unroll
    for (int i = 0; i < 4; ++i) {
      int grow = rbase + i;
      if (grow < n) {
        float s = dinv[grow];
        __half* gp = G_out + (size_t)grow * OSTR + mrow;
#pragma unroll
        for (int nt = 0; nt < NT; ++nt) {
          if (OSTR == 128 || nt * 16 + mrow < 40)
            gp[nt * 16] = __float2half_rn(s * acc[mt][nt][i]);
        }
      }
    }
  }
}

// M=40 aggregate (unweighted: G pre-scaled), R14 form. G40 rows at 128B
// stride = 16 float2 per row -> one aligned line per gather.
__global__ __launch_bounds__(256)
void aggregate40_kernel(const __half* __restrict__ G, const int* __restrict__ rowptr,
                        const int* __restrict__ col, const float* __restrict__ dinv,
                        const float* __restrict__ bias, float* __restrict__ out,
                        int n) {
  constexpr int NPW = 4;
  int wid = threadIdx.x >> 6;
  int lane = threadIdx.x & 63;
  int n0 = (blockIdx.x * 4 + wid) * NPW;
  if (n0 >= n) return;

  int sub = lane / 10;    // 0..6 (6 = idle)
  int c = lane % 10;
  bool act = sub < 6;
  const float2* g2 = (const float2*)G;   // row stride = 16 float2 (128B)

  int eA = rowptr[n0], endA = rowptr[n0 + 1];
  int n1 = min(n0 + 1, n - 1);
  int eB = rowptr[n1], endB = rowptr[n1 + 1];

  int lastA = (endA > eA) ? endA - 1 : 0;
  int iA = eA + sub * 4;
  int cA0 = col[min(iA,     lastA)];
  int cA1 = col[min(iA + 1, lastA)];
  int cA2 = col[min(iA + 2, lastA)];
  int cA3 = col[min(iA + 3, lastA)];

#pragma unroll
  for (int j = 0; j < NPW; ++j) {
    int node = n0 + j;
    if (node >= n) break;

    float2 r0 = g2[(size_t)cA0 * 16 + c];
    float2 r1 = g2[(size_t)cA1 * 16 + c];
    float2 r2 = g2[(size_t)cA2 * 16 + c];
    float2 r3 = g2[(size_t)cA3 * 16 + c];
    float2 rs = g2[(size_t)node * 16 + c];
    float di = dinv[node];

    int n2 = min(node + 2, n - 1);
    int eC = rowptr[n2];
    int endC = rowptr[n2 + 1];

    int lastB = (endB > eB) ? endB - 1 : 0;
    int iB = eB + sub * 4;
    int cB0 = col[min(iB,     lastB)];
    int cB1 = col[min(iB + 1, lastB)];
    int cB2 = col[min(iB + 2, lastB)];
    int cB3 = col[min(iB + 3, lastB)];

    float ax = 0.f, ay = 0.f, az = 0.f, aw = 0.f;
    auto acc2w = [&](float2 raw, float w) {
      float2 f0 = __half22float2(*(const __half2*)&raw.x);
      float2 f1 = __half22float2(*(const __half2*)&raw.y);
      ax = fmaf(w, f0.x, ax); ay = fmaf(w, f0.y, ay);
      az = fmaf(w, f1.x, az); aw = fmaf(w, f1.y, aw);
    };
    acc2w(rs, (lane < 10) ? 1.f : 0.f);  // self-loop
    acc2w(r0, (act && iA     < endA) ? 1.f : 0.f);
    acc2w(r1, (act && iA + 1 < endA) ? 1.f : 0.f);
    acc2w(r2, (act && iA + 2 < endA) ? 1.f : 0.f);
    acc2w(r3, (act && iA + 3 < endA) ? 1.f : 0.f);

    for (int t = eA + 24; t < endA; t += 6) {
      int it = t + sub;
      if (act && it < endA) {
        int sc = col[it];
        acc2w(g2[(size_t)sc * 16 + c], 1.f);
      }
    }

    float bx = __shfl(ax, lane + 30), by = __shfl(ay, lane + 30),
          bz = __shfl(az, lane + 30), bw = __shfl(aw, lane + 30);
    ax += bx; ay += by; az += bz; aw += bw;
    float c1x = __shfl(ax, lane + 10), c1y = __shfl(ay, lane + 10),
          c1z = __shfl(az, lane + 10), c1w = __shfl(aw, lane + 10);
    float c2x = __shfl(ax, lane + 20), c2y = __shfl(ay, lane + 20),
          c2z = __shfl(az, lane + 20), c2w = __shfl(aw, lane + 20);

    if (lane < 10) {
      float sx = ax + c1x + c2x;
      float sy = ay + c1y + c2y;
      float sz = az + c1z + c2z;
      float sw = aw + c1w + c2w;
      float4 bb = ((const float4*)bias)[c];
      float4 o = make_float4(di * sx + bb.x, di * sy + bb.y, di * sz + bb.z,
                             di * sw + bb.w);
      ((float4*)out)[(size_t)node * 10 + c] = o;
    }

    eA = eB; endA = endB; eB = eC; endB = endC;
    iA = eA + sub * 4;
    cA0 = cB0; cA1 = cB1; cA2 = cB2; cA3 = cB3;
  }
}

extern "C" void kernel_launch(void* const* d_in, const int* in_sizes, int n_in,
                              void* d_out, int out_size, void* d_ws, size_t ws_size,
                              hipStream_t stream) {
  const float* x = (const float*)d_in[0];
  const float* W0 = (const float*)d_in[1];
  const float* b0 = (const float*)d_in[2];
  const float* W1 = (const float*)d_in[3];
  const float* b1 = (const float*)d_in[4];
  const float* W2 = (const float*)d_in[5];
  const float* b2 = (const float*)d_in[6];
  const int* ei = (const int*)d_in[7];

  const int N = in_sizes[0] / 128;
  const int E = in_sizes[7] / 2;
  const int* src = ei;
  const int* dst = ei + E;
  const int NB = (N + 255) >> 8;

  char* w = (char*)d_ws;
  size_t off = 0;
  auto alloc = [&](size_t bytes) -> void* {
    void* p = w + off;
    off = (off + bytes + 255) & ~(size_t)255;
    return p;
  };
  int* bucket_cnt = (int*)alloc((size_t)NBMAX * 4);
  float* dinv = (float*)alloc((size_t)N * 4);
  int* rowptr = (int*)alloc((size_t)(N + 1) * 4);
  int* col = (int*)alloc((size_t)E * 4);
  unsigned* bucketbuf = (unsigned*)alloc((size_t)NB * CAP * 4);
  __half* gbuf = (__half*)alloc((size_t)N * 128 * 2);
  __half* hbuf = (__half*)alloc((size_t)N * 128 * 2);
  __half* w0t = (__half*)alloc(128 * 128 * 2);
  __half* w1t = (__half*)alloc(128 * 128 * 2);
  __half* w2t = (__half*)alloc(48 * 128 * 2);
  (void)ws_size;

  hipMemsetAsync(bucket_cnt, 0, (size_t)NBMAX * 4, stream);

  dim3 blk(256);
  int gP1 = (E + 4095) / 4096;
  int gW = (38912 + 255) / 256;
  int gGemm = (N + 127) / 128;
  int gAgg = (N + 15) / 16;    // 4 waves x NPW=4 nodes

  // K1: bucket partition (single-pass) + W transpose prep
  bucket_prep_kernel<<<gP1 + gW, blk, 0, stream>>>(src, dst, E, gP1, NB,
                                                   bucket_cnt, bucketbuf,
                                                   W0, W1, W2, w0t, w1t, w2t);
  // K2: CSR build blocks first (latency-bound), then MFMA gemm layer-0
  gemm128_build_kernel<<<gGemm + NB, blk, 0, stream>>>(x, w0t, gbuf, N,
                                                       bucketbuf, bucket_cnt,
                                                       rowptr, dinv, col, N, E, NB);

  // FUSED layer-1: agg(gbuf, weighted, b0, ReLU) -> gemm(w1t, dinv) -> hbuf
  agg_gemm_kernel<true, 8, 128><<<gGemm, blk, 0, stream>>>(
      gbuf, rowptr, col, dinv, b0, w1t, hbuf, N);
  // FUSED layer-2: agg(hbuf, unweighted, b1, ReLU) -> gemm48(w2t, dinv) -> gbuf
  agg_gemm_kernel<false, 3, 64><<<gGemm, blk, 0, stream>>>(
      hbuf, rowptr, col, dinv, b1, w2t, gbuf, N);

  aggregate40_kernel<<<gAgg, blk, 0, stream>>>(gbuf, rowptr, col, dinv, b2,
                                               (float*)d_out, N);
}